// Round 1
// baseline (871.437 us; speedup 1.0000x reference)
//
#include <hip/hip_runtime.h>

// HybridMixSTEDecoder: 5 group-GEMMs (M=27648, K=512, N in {81,81,135,81,81})
// out(b, t=tp*9+pt, j=group[gl], c) = sum_h tokens[b,tp,i,h]*W_i[n,h] + b_i[n]
// with n = pt*(gs*3) + gl*3 + c.  Joint groups partition J=17 -> count==1,
// division is a no-op, every output element written exactly once.

constexpr int HID   = 512;
constexpr int TPCH  = 27;          // T_patches
constexpr int MROWS = 1024 * TPCH; // 27648
constexpr int BM    = 128;
constexpr int BK    = 32;
constexpr int LDSS  = BK + 4;      // 36 floats: float4-aligned, bank-spread
constexpr int TPB   = 256;

struct Args {
  const float* W[5];
  const float* bias[5];
};

template <int GS, int TN, int NP>
__device__ __forceinline__ void gemm_body(const float* __restrict__ tokens,
                                          const float* __restrict__ W,
                                          const float* __restrict__ bias,
                                          float* __restrict__ out,
                                          int gslice, int jbase,
                                          float* As, float* Ws, int m0, int tid) {
  constexpr int N = 27 * GS;          // 81 or 135
  const int nt = tid & 7;             // 8 threads along N
  const int mt = tid >> 3;            // 32 threads along M

  float acc[4][TN] = {};

  for (int k0 = 0; k0 < HID; k0 += BK) {
    // --- stage tokens tile: BM rows x BK floats (row stride G*H = 2560) ---
    const float* srcA = tokens + (size_t)m0 * (5 * HID) + gslice * HID + k0;
    #pragma unroll
    for (int it = 0; it < (BM * (BK / 4)) / TPB; ++it) {   // 4 iters
      int q   = tid + it * TPB;
      int row = q >> 3;          // BK/4 = 8 float4 per row
      int kq  = q & 7;
      float4 v = *reinterpret_cast<const float4*>(srcA + row * (5 * HID) + kq * 4);
      *reinterpret_cast<float4*>(As + row * LDSS + kq * 4) = v;
    }
    // --- stage W tile: NP rows x BK floats (rows >= N zero-padded) ---
    #pragma unroll
    for (int it = 0; it < (NP * (BK / 4) + TPB - 1) / TPB; ++it) {
      int q = tid + it * TPB;
      if (q < NP * (BK / 4)) {
        int row = q >> 3;
        int kq  = q & 7;
        float4 v = make_float4(0.f, 0.f, 0.f, 0.f);
        if (row < N)
          v = *reinterpret_cast<const float4*>(W + (size_t)row * HID + k0 + kq * 4);
        *reinterpret_cast<float4*>(Ws + row * LDSS + kq * 4) = v;
      }
    }
    __syncthreads();

    // --- compute: per k4-step, 4 + TN ds_read_b128, 16*TN v_fma_f32 ---
    #pragma unroll 4
    for (int kk = 0; kk < BK / 4; ++kk) {
      float4 a[4];
      #pragma unroll
      for (int tm = 0; tm < 4; ++tm)
        a[tm] = *reinterpret_cast<const float4*>(As + (mt + 32 * tm) * LDSS + kk * 4);
      #pragma unroll
      for (int tn = 0; tn < TN; ++tn) {
        float4 w = *reinterpret_cast<const float4*>(Ws + (nt + 8 * tn) * LDSS + kk * 4);
        #pragma unroll
        for (int tm = 0; tm < 4; ++tm) {
          acc[tm][tn] = fmaf(a[tm].x, w.x, acc[tm][tn]);
          acc[tm][tn] = fmaf(a[tm].y, w.y, acc[tm][tn]);
          acc[tm][tn] = fmaf(a[tm].z, w.z, acc[tm][tn]);
          acc[tm][tn] = fmaf(a[tm].w, w.w, acc[tm][tn]);
        }
      }
    }
    __syncthreads();
  }

  // --- epilogue: bias + scatter store (each element written exactly once) ---
  #pragma unroll
  for (int tn = 0; tn < TN; ++tn) {
    int n = nt + 8 * tn;
    if (n < N) {
      float bv  = bias[n];
      int pt    = n / (3 * GS);
      int rem   = n - pt * (3 * GS);
      int gl    = rem / 3;
      int c     = rem - gl * 3;
      int j     = (GS == 3) ? (jbase + gl) : (gl == 0 ? 0 : gl + 6);
      #pragma unroll
      for (int tm = 0; tm < 4; ++tm) {
        int m  = m0 + mt + 32 * tm;
        int b  = m / TPCH;
        int tp = m - b * TPCH;
        int t  = tp * 9 + pt;
        out[((size_t)(b * 243 + t) * 17 + j) * 3 + c] = acc[tm][tn] + bv;
      }
    }
  }
}

__global__ __launch_bounds__(TPB)
void decoder_kernel(const float* __restrict__ tokens, Args args,
                    float* __restrict__ out) {
  __shared__ float As[BM * LDSS];     // 18432 B
  __shared__ float Ws[136 * LDSS];    // 19584 B  (max over groups)
  const int tid = threadIdx.x;
  const int m0  = blockIdx.x * BM;
  const int grp = blockIdx.y;         // uniform per block

  if (grp == 2) {
    gemm_body<5, 17, 136>(tokens, args.W[2], args.bias[2], out, 2, 0, As, Ws, m0, tid);
  } else {
    int jbase = (grp == 0) ? 1 : (grp == 1) ? 4 : (grp == 3) ? 11 : 14;
    gemm_body<3, 11, 88>(tokens, args.W[grp], args.bias[grp], out, grp, jbase, As, Ws, m0, tid);
  }
}

extern "C" void kernel_launch(void* const* d_in, const int* in_sizes, int n_in,
                              void* d_out, int out_size, void* d_ws, size_t ws_size,
                              hipStream_t stream) {
  const float* tokens = reinterpret_cast<const float*>(d_in[0]);
  Args args;
  for (int i = 0; i < 5; ++i) {
    args.W[i]    = reinterpret_cast<const float*>(d_in[1 + 2 * i]);
    args.bias[i] = reinterpret_cast<const float*>(d_in[2 + 2 * i]);
  }
  float* out = reinterpret_cast<float*>(d_out);

  dim3 grid(MROWS / BM, 5);   // (216, 5)
  decoder_kernel<<<grid, TPB, 0, stream>>>(tokens, args, out);
}

// Round 4
// 555.762 us; speedup vs baseline: 1.5680x; 1.5680x over previous
//
#include <hip/hip_runtime.h>
#include <cstdint>

// HybridMixSTEDecoder via bf16 hi/lo split MFMA (3 products ~ fp32 accuracy).
// 5 group-GEMMs: M=27648, K=512, N in {81,81,135,81,81} (padded to 96/144).
// Joint groups partition J=17 -> every output element written exactly once.
// A (tokens) has no cross-wave reuse -> no LDS, direct global fragment loads.
// W pre-split to bf16 hi/lo in d_ws by a prologue kernel (runs every call).

typedef __attribute__((ext_vector_type(8))) short short8;
typedef __attribute__((ext_vector_type(4))) float f32x4;
typedef __attribute__((ext_vector_type(4))) uint32_t u32x4;

constexpr int HID   = 512;
constexpr int TPCH  = 27;
constexpr int MROWS = 1024 * TPCH;   // 27648
constexpr int RTOT  = 528;           // padded W rows: 96+96+144+96+96

struct Args {
  const float* W[5];
  const float* bias[5];
};

__device__ __forceinline__ uint32_t fbits(float x) {
  union { float f; uint32_t u; } v; v.f = x; return v.u;
}
__device__ __forceinline__ float bfloat(uint32_t u) {
  union { float f; uint32_t u; } v; v.u = u; return v.f;
}

// ---------- prologue: split W into truncated-bf16 hi/lo pairs in ws ----------
// ws layout (ushort): row r (padded, 528 total) occupies 1024 ushorts:
//   [0..511] = hi bf16 of W[n][k],  [512..1023] = lo bf16. Padded rows = 0.
__global__ __launch_bounds__(256) void convert_w(Args args, unsigned short* ws) {
  int idx = blockIdx.x * 256 + threadIdx.x;
  if (idx >= RTOT * HID) return;
  int nrow = idx >> 9;
  int k    = idx & (HID - 1);
  const float* Wg; int n; int nreal;
  if      (nrow < 96)  { Wg = args.W[0]; n = nrow;       nreal = 81;  }
  else if (nrow < 192) { Wg = args.W[1]; n = nrow - 96;  nreal = 81;  }
  else if (nrow < 336) { Wg = args.W[2]; n = nrow - 192; nreal = 135; }
  else if (nrow < 432) { Wg = args.W[3]; n = nrow - 336; nreal = 81;  }
  else                 { Wg = args.W[4]; n = nrow - 432; nreal = 81;  }
  float x = (n < nreal) ? Wg[(size_t)n * HID + k] : 0.f;
  uint32_t u = fbits(x);
  float r = x - bfloat(u & 0xFFFF0000u);   // exact (operands agree to 8 bits)
  ws[(size_t)nrow * 1024 + k]       = (unsigned short)(u >> 16);
  ws[(size_t)nrow * 1024 + 512 + k] = (unsigned short)(fbits(r) >> 16);
}

// ---------- fragment packing: 8 fp32 (2x u32x4) -> bf16x8 hi / lo ----------
__device__ __forceinline__ short8 pack_hi(u32x4 a, u32x4 b) {
  union { uint32_t u[4]; short8 s; } cv;
  cv.u[0] = (a[0] >> 16) | (a[1] & 0xFFFF0000u);
  cv.u[1] = (a[2] >> 16) | (a[3] & 0xFFFF0000u);
  cv.u[2] = (b[0] >> 16) | (b[1] & 0xFFFF0000u);
  cv.u[3] = (b[2] >> 16) | (b[3] & 0xFFFF0000u);
  return cv.s;
}
__device__ __forceinline__ short8 pack_lo(u32x4 a, u32x4 b) {
  union { uint32_t u[4]; short8 s; } cv;
  #pragma unroll
  for (int p = 0; p < 4; ++p) {
    uint32_t u0 = (p < 2) ? a[2 * p]     : b[2 * (p - 2)];
    uint32_t u1 = (p < 2) ? a[2 * p + 1] : b[2 * (p - 2) + 1];
    float r0 = bfloat(u0) - bfloat(u0 & 0xFFFF0000u);
    float r1 = bfloat(u1) - bfloat(u1 & 0xFFFF0000u);
    cv.u[p] = (fbits(r0) >> 16) | (fbits(r1) & 0xFFFF0000u);
  }
  return cv.s;
}

// ---------- main GEMM body (per wave: 32 rows x full padded N) ----------
template <int GS, int NR>   // NR = padded N / 16 (6 or 9)
__device__ __forceinline__ void mfma_body(const float* __restrict__ tokens,
                                          const unsigned short* __restrict__ ws,
                                          const float* __restrict__ bias,
                                          float* __restrict__ out,
                                          int g, int rbase, int jbase) {
  constexpr int N = 27 * GS;           // 81 or 135
  const int lane = threadIdx.x & 63;
  const int wave = threadIdx.x >> 6;
  const int m0   = blockIdx.x * 128 + wave * 32;  // wave owns rows m0..m0+31
  const int l15  = lane & 15;          // A row / B col / C col within tile
  const int koff = (lane >> 4) * 8;    // k sub-chunk

  // acc init = bias (broadcast along rows); padded cols get 0
  f32x4 acc[2][NR];
  #pragma unroll
  for (int nr = 0; nr < NR; ++nr) {
    int n = nr * 16 + l15;
    float bv = (n < N) ? bias[n] : 0.f;
    f32x4 b4 = {bv, bv, bv, bv};
    acc[0][nr] = b4;
    acc[1][nr] = b4;
  }

  const float* aptr0 = tokens + (size_t)(m0 + l15) * (5 * HID) + g * HID + koff;
  const float* aptr1 = aptr0 + (size_t)16 * (5 * HID);
  const unsigned short* bbase = ws + (size_t)rbase * 1024 + koff;

  for (int kc = 0; kc < HID / 32; ++kc) {       // 16 k-chunks of 32
    u32x4 a0a = *reinterpret_cast<const u32x4*>(aptr0 + kc * 32);
    u32x4 a0b = *reinterpret_cast<const u32x4*>(aptr0 + kc * 32 + 4);
    u32x4 a1a = *reinterpret_cast<const u32x4*>(aptr1 + kc * 32);
    u32x4 a1b = *reinterpret_cast<const u32x4*>(aptr1 + kc * 32 + 4);
    short8 ah0 = pack_hi(a0a, a0b), al0 = pack_lo(a0a, a0b);
    short8 ah1 = pack_hi(a1a, a1b), al1 = pack_lo(a1a, a1b);
    #pragma unroll
    for (int nr = 0; nr < NR; ++nr) {
      const unsigned short* bp = bbase + (size_t)(nr * 16 + l15) * 1024 + kc * 32;
      short8 bh = *reinterpret_cast<const short8*>(bp);
      short8 bl = *reinterpret_cast<const short8*>(bp + 512);
      acc[0][nr] = __builtin_amdgcn_mfma_f32_16x16x32_bf16(ah0, bh, acc[0][nr], 0, 0, 0);
      acc[1][nr] = __builtin_amdgcn_mfma_f32_16x16x32_bf16(ah1, bh, acc[1][nr], 0, 0, 0);
      acc[0][nr] = __builtin_amdgcn_mfma_f32_16x16x32_bf16(al0, bh, acc[0][nr], 0, 0, 0);
      acc[1][nr] = __builtin_amdgcn_mfma_f32_16x16x32_bf16(al1, bh, acc[1][nr], 0, 0, 0);
      acc[0][nr] = __builtin_amdgcn_mfma_f32_16x16x32_bf16(ah0, bl, acc[0][nr], 0, 0, 0);
      acc[1][nr] = __builtin_amdgcn_mfma_f32_16x16x32_bf16(ah1, bl, acc[1][nr], 0, 0, 0);
    }
  }

  // epilogue: scatter store. C/D layout: col = lane&15, row = (lane>>4)*4 + reg
  #pragma unroll
  for (int mt = 0; mt < 2; ++mt) {
    int mrow = m0 + mt * 16 + (lane >> 4) * 4;
    #pragma unroll
    for (int nr = 0; nr < NR; ++nr) {
      int n = nr * 16 + l15;
      if (n < N) {
        int pt  = n / (3 * GS);
        int rem = n - pt * (3 * GS);
        int gl  = rem / 3;
        int c   = rem - gl * 3;
        int j   = (GS == 5) ? (gl == 0 ? 0 : gl + 6) : (jbase + gl);
        #pragma unroll
        for (int r = 0; r < 4; ++r) {
          int m  = mrow + r;
          int b  = m / TPCH;
          int tp = m - b * TPCH;
          out[((size_t)(b * 243 + tp * 9 + pt) * 17 + j) * 3 + c] = acc[mt][nr][r];
        }
      }
    }
  }
}

__global__ __launch_bounds__(256)
void decoder_mfma(const float* __restrict__ tokens, Args args,
                  const unsigned short* __restrict__ ws, float* __restrict__ out) {
  const int g = blockIdx.y;   // uniform per block
  if (g == 2) {
    mfma_body<5, 9>(tokens, ws, args.bias[2], out, 2, 192, 0);
  } else {
    int jbase = (g == 0) ? 1 : (g == 1) ? 4 : (g == 3) ? 11 : 14;
    int rbase = (g == 0) ? 0 : (g == 1) ? 96 : (g == 3) ? 336 : 432;
    mfma_body<3, 6>(tokens, ws, args.bias[g], out, g, rbase, jbase);
  }
}

extern "C" void kernel_launch(void* const* d_in, const int* in_sizes, int n_in,
                              void* d_out, int out_size, void* d_ws, size_t ws_size,
                              hipStream_t stream) {
  const float* tokens = reinterpret_cast<const float*>(d_in[0]);
  Args args;
  for (int i = 0; i < 5; ++i) {
    args.W[i]    = reinterpret_cast<const float*>(d_in[1 + 2 * i]);
    args.bias[i] = reinterpret_cast<const float*>(d_in[2 + 2 * i]);
  }
  float* out = reinterpret_cast<float*>(d_out);
  unsigned short* ws = reinterpret_cast<unsigned short*>(d_ws);  // needs 1.03 MB

  convert_w<<<(RTOT * HID + 255) / 256, 256, 0, stream>>>(args, ws);
  decoder_mfma<<<dim3(MROWS / 128, 5), 256, 0, stream>>>(tokens, args, ws, out);
}

// Round 7
// 527.219 us; speedup vs baseline: 1.6529x; 1.0541x over previous
//
#include <hip/hip_runtime.h>
#include <cstdint>

// HybridMixSTEDecoder via bf16 hi/lo split MFMA (3 products ~ fp32 accuracy).
// R5: latency-hiding restructure. Per k-chunk: ALL B fragments loaded into
// register arrays up-front (12-18 loads in flight), A double-buffered in
// registers (kc+1 prefetched before kc's MFMA burst). No LDS, no barriers.

typedef __attribute__((ext_vector_type(8))) short short8;
typedef __attribute__((ext_vector_type(4))) float f32x4;
typedef __attribute__((ext_vector_type(4))) uint32_t u32x4;

constexpr int HID   = 512;
constexpr int TPCH  = 27;
constexpr int MROWS = 1024 * TPCH;   // 27648
constexpr int RTOT  = 528;           // padded W rows: 96+96+144+96+96

struct Args {
  const float* W[5];
  const float* bias[5];
};

__device__ __forceinline__ uint32_t fbits(float x) {
  union { float f; uint32_t u; } v; v.f = x; return v.u;
}
__device__ __forceinline__ float bfloat(uint32_t u) {
  union { float f; uint32_t u; } v; v.u = u; return v.f;
}

// ---------- prologue: split W into truncated-bf16 hi/lo pairs in ws ----------
// ws layout (ushort): row r (padded, 528 total) occupies 1024 ushorts:
//   [0..511] = hi bf16 of W[n][k],  [512..1023] = lo bf16. Padded rows = 0.
__global__ __launch_bounds__(256) void convert_w(Args args, unsigned short* ws) {
  int idx = blockIdx.x * 256 + threadIdx.x;
  if (idx >= RTOT * HID) return;
  int nrow = idx >> 9;
  int k    = idx & (HID - 1);
  const float* Wg; int n; int nreal;
  if      (nrow < 96)  { Wg = args.W[0]; n = nrow;       nreal = 81;  }
  else if (nrow < 192) { Wg = args.W[1]; n = nrow - 96;  nreal = 81;  }
  else if (nrow < 336) { Wg = args.W[2]; n = nrow - 192; nreal = 135; }
  else if (nrow < 432) { Wg = args.W[3]; n = nrow - 336; nreal = 81;  }
  else                 { Wg = args.W[4]; n = nrow - 432; nreal = 81;  }
  float x = (n < nreal) ? Wg[(size_t)n * HID + k] : 0.f;
  uint32_t u = fbits(x);
  float r = x - bfloat(u & 0xFFFF0000u);   // exact (operands agree to 8 bits)
  ws[(size_t)nrow * 1024 + k]       = (unsigned short)(u >> 16);
  ws[(size_t)nrow * 1024 + 512 + k] = (unsigned short)(fbits(r) >> 16);
}

// ---------- fragment packing: 8 fp32 (2x u32x4) -> bf16x8 hi / lo ----------
__device__ __forceinline__ short8 pack_hi(u32x4 a, u32x4 b) {
  union { uint32_t u[4]; short8 s; } cv;
  cv.u[0] = (a[0] >> 16) | (a[1] & 0xFFFF0000u);
  cv.u[1] = (a[2] >> 16) | (a[3] & 0xFFFF0000u);
  cv.u[2] = (b[0] >> 16) | (b[1] & 0xFFFF0000u);
  cv.u[3] = (b[2] >> 16) | (b[3] & 0xFFFF0000u);
  return cv.s;
}
__device__ __forceinline__ short8 pack_lo(u32x4 a, u32x4 b) {
  union { uint32_t u[4]; short8 s; } cv;
  #pragma unroll
  for (int p = 0; p < 4; ++p) {
    uint32_t u0 = (p < 2) ? a[2 * p]     : b[2 * (p - 2)];
    uint32_t u1 = (p < 2) ? a[2 * p + 1] : b[2 * (p - 2) + 1];
    float r0 = bfloat(u0) - bfloat(u0 & 0xFFFF0000u);
    float r1 = bfloat(u1) - bfloat(u1 & 0xFFFF0000u);
    cv.u[p] = (fbits(r0) >> 16) | (fbits(r1) & 0xFFFF0000u);
  }
  return cv.s;
}

// ---------- main GEMM body (per wave: 32 rows x full padded N) ----------
template <int GS, int NR>   // NR = padded N / 16 (6 or 9)
__device__ __forceinline__ void mfma_body(const float* __restrict__ tokens,
                                          const unsigned short* __restrict__ ws,
                                          const float* __restrict__ bias,
                                          float* __restrict__ out,
                                          int g, int rbase, int jbase) {
  constexpr int N = 27 * GS;           // 81 or 135
  const int lane = threadIdx.x & 63;
  const int wave = threadIdx.x >> 6;
  const int m0   = blockIdx.x * 128 + wave * 32;  // wave owns rows m0..m0+31
  const int l15  = lane & 15;          // A row / B col / C col within tile
  const int koff = (lane >> 4) * 8;    // k sub-chunk

  // acc init = bias (broadcast along rows); padded cols get 0
  f32x4 acc[2][NR];
  #pragma unroll
  for (int nr = 0; nr < NR; ++nr) {
    int n = nr * 16 + l15;
    float bv = (n < N) ? bias[n] : 0.f;
    f32x4 b4 = {bv, bv, bv, bv};
    acc[0][nr] = b4;
    acc[1][nr] = b4;
  }

  const float* aptr0 = tokens + (size_t)(m0 + l15) * (5 * HID) + g * HID + koff;
  const float* aptr1 = aptr0 + (size_t)16 * (5 * HID);
  const unsigned short* bbase = ws + (size_t)rbase * 1024 + koff;

  // A double-buffer: cur holds kc's raw fp32, nxt receives kc+1's.
  u32x4 c0a = *reinterpret_cast<const u32x4*>(aptr0);
  u32x4 c0b = *reinterpret_cast<const u32x4*>(aptr0 + 4);
  u32x4 c1a = *reinterpret_cast<const u32x4*>(aptr1);
  u32x4 c1b = *reinterpret_cast<const u32x4*>(aptr1 + 4);

  #pragma unroll 2
  for (int kc = 0; kc < 16; ++kc) {
    // ---- issue ALL B loads for this kc (2*NR independent 16B loads) ----
    short8 bh[NR], bl[NR];
    #pragma unroll
    for (int nr = 0; nr < NR; ++nr) {
      const unsigned short* bp = bbase + (size_t)(nr * 16 + l15) * 1024 + kc * 32;
      bh[nr] = *reinterpret_cast<const short8*>(bp);
      bl[nr] = *reinterpret_cast<const short8*>(bp + 512);
    }
    // ---- issue next-kc A loads (HBM stream; kc=15 reloads kc=0, L1-hot) ----
    const int kn = (kc + 1) & 15;
    u32x4 n0a = *reinterpret_cast<const u32x4*>(aptr0 + kn * 32);
    u32x4 n0b = *reinterpret_cast<const u32x4*>(aptr0 + kn * 32 + 4);
    u32x4 n1a = *reinterpret_cast<const u32x4*>(aptr1 + kn * 32);
    u32x4 n1b = *reinterpret_cast<const u32x4*>(aptr1 + kn * 32 + 4);
    // ---- pack current A (VALU, overlaps in-flight loads) ----
    short8 ah0 = pack_hi(c0a, c0b), al0 = pack_lo(c0a, c0b);
    short8 ah1 = pack_hi(c1a, c1b), al1 = pack_lo(c1a, c1b);
    // ---- MFMA burst (waits roll through bh/bl in issue order) ----
    #pragma unroll
    for (int nr = 0; nr < NR; ++nr) {
      acc[0][nr] = __builtin_amdgcn_mfma_f32_16x16x32_bf16(ah0, bh[nr], acc[0][nr], 0, 0, 0);
      acc[1][nr] = __builtin_amdgcn_mfma_f32_16x16x32_bf16(ah1, bh[nr], acc[1][nr], 0, 0, 0);
      acc[0][nr] = __builtin_amdgcn_mfma_f32_16x16x32_bf16(al0, bh[nr], acc[0][nr], 0, 0, 0);
      acc[1][nr] = __builtin_amdgcn_mfma_f32_16x16x32_bf16(al1, bh[nr], acc[1][nr], 0, 0, 0);
      acc[0][nr] = __builtin_amdgcn_mfma_f32_16x16x32_bf16(ah0, bl[nr], acc[0][nr], 0, 0, 0);
      acc[1][nr] = __builtin_amdgcn_mfma_f32_16x16x32_bf16(ah1, bl[nr], acc[1][nr], 0, 0, 0);
    }
    c0a = n0a; c0b = n0b; c1a = n1a; c1b = n1b;
  }

  // epilogue: scatter store. C/D layout: col = lane&15, row = (lane>>4)*4 + reg
  #pragma unroll
  for (int mt = 0; mt < 2; ++mt) {
    int mrow = m0 + mt * 16 + (lane >> 4) * 4;
    #pragma unroll
    for (int nr = 0; nr < NR; ++nr) {
      int n = nr * 16 + l15;
      if (n < N) {
        int pt  = n / (3 * GS);
        int rem = n - pt * (3 * GS);
        int gl  = rem / 3;
        int c   = rem - gl * 3;
        int j   = (GS == 5) ? (gl == 0 ? 0 : gl + 6) : (jbase + gl);
        #pragma unroll
        for (int r = 0; r < 4; ++r) {
          int m  = mrow + r;
          int b  = m / TPCH;
          int tp = m - b * TPCH;
          out[((size_t)(b * 243 + tp * 9 + pt) * 17 + j) * 3 + c] = acc[mt][nr][r];
        }
      }
    }
  }
}

__global__ __launch_bounds__(256)
void decoder_mfma(const float* __restrict__ tokens, Args args,
                  const unsigned short* __restrict__ ws, float* __restrict__ out) {
  const int g = blockIdx.y;   // uniform per block
  if (g == 2) {
    mfma_body<5, 9>(tokens, ws, args.bias[2], out, 2, 192, 0);
  } else {
    int jbase = (g == 0) ? 1 : (g == 1) ? 4 : (g == 3) ? 11 : 14;
    int rbase = (g == 0) ? 0 : (g == 1) ? 96 : (g == 3) ? 336 : 432;
    mfma_body<3, 6>(tokens, ws, args.bias[g], out, g, rbase, jbase);
  }
}

extern "C" void kernel_launch(void* const* d_in, const int* in_sizes, int n_in,
                              void* d_out, int out_size, void* d_ws, size_t ws_size,
                              hipStream_t stream) {
  const float* tokens = reinterpret_cast<const float*>(d_in[0]);
  Args args;
  for (int i = 0; i < 5; ++i) {
    args.W[i]    = reinterpret_cast<const float*>(d_in[1 + 2 * i]);
    args.bias[i] = reinterpret_cast<const float*>(d_in[2 + 2 * i]);
  }
  float* out = reinterpret_cast<float*>(d_out);
  unsigned short* ws = reinterpret_cast<unsigned short*>(d_ws);  // needs 1.03 MB

  convert_w<<<(RTOT * HID + 255) / 256, 256, 0, stream>>>(args, ws);
  decoder_mfma<<<dim3(MROWS / 128, 5), 256, 0, stream>>>(tokens, args, ws, out);
}

// Round 9
// 484.166 us; speedup vs baseline: 1.7999x; 1.0889x over previous
//
#include <hip/hip_runtime.h>
#include <cstdint>

// HybridMixSTEDecoder via bf16 hi/lo split MFMA (3 products ~ fp32 accuracy).
// R8: (1) __launch_bounds__(256,2) -> 256-VGPR budget so the batched loads
// stay in flight (R7's VGPR=108 proved the compiler serialized them);
// (2) ws re-laid out FRAGMENT-MAJOR: each (kc, hi/lo, nr) B-fragment is 64
// lanes x 16B contiguous (1KB per wave load, fully coalesced, shared across
// the block's 4 waves) instead of 16 lines scattered 2KB apart.

typedef __attribute__((ext_vector_type(8))) short short8;
typedef __attribute__((ext_vector_type(4))) float f32x4;
typedef __attribute__((ext_vector_type(4))) uint32_t u32x4;

constexpr int HID   = 512;
constexpr int TPCH  = 27;
constexpr int MROWS = 1024 * TPCH;   // 27648
// fragment-major ws: group g has NRg*16kc*2(h)*64lane fragments of 8 ushorts.
// frag counts: GS3 = 12288, GS5 = 18432; cum = 0,12288,24576,43008,55296,67584
constexpr int FRAG_TOT = 67584;      // * 16B = 1.03 MB ws

struct Args {
  const float* W[5];
  const float* bias[5];
};

__device__ __forceinline__ uint32_t fbits(float x) {
  union { float f; uint32_t u; } v; v.f = x; return v.u;
}
__device__ __forceinline__ float bfloat(uint32_t u) {
  union { float f; uint32_t u; } v; v.u = u; return v.f;
}

// ---------- fragment packing: 8 fp32 (2x u32x4) -> bf16x8 hi / lo ----------
__device__ __forceinline__ short8 pack_hi(u32x4 a, u32x4 b) {
  union { uint32_t u[4]; short8 s; } cv;
  cv.u[0] = (a[0] >> 16) | (a[1] & 0xFFFF0000u);
  cv.u[1] = (a[2] >> 16) | (a[3] & 0xFFFF0000u);
  cv.u[2] = (b[0] >> 16) | (b[1] & 0xFFFF0000u);
  cv.u[3] = (b[2] >> 16) | (b[3] & 0xFFFF0000u);
  return cv.s;
}
__device__ __forceinline__ short8 pack_lo(u32x4 a, u32x4 b) {
  union { uint32_t u[4]; short8 s; } cv;
  #pragma unroll
  for (int p = 0; p < 4; ++p) {
    uint32_t u0 = (p < 2) ? a[2 * p]     : b[2 * (p - 2)];
    uint32_t u1 = (p < 2) ? a[2 * p + 1] : b[2 * (p - 2) + 1];
    float r0 = bfloat(u0) - bfloat(u0 & 0xFFFF0000u);
    float r1 = bfloat(u1) - bfloat(u1 & 0xFFFF0000u);
    cv.u[p] = (fbits(r0) >> 16) | (fbits(r1) & 0xFFFF0000u);
  }
  return cv.s;
}

// ---------- prologue: W -> fragment-major bf16 hi/lo fragments in ws -------
// fragment f (within group): lane = f&63, nr = (f>>6)%NR, h = ((f>>6)/NR)&1,
// kc = ((f>>6)/NR)>>1.  Element j of fragment = W[nr*16+(lane&15)]
// [kc*32+(lane>>4)*8+j], j=0..7 (matches MFMA bf16x8 k-consecutive layout).
__global__ __launch_bounds__(256) void convert_w(Args args, unsigned short* ws) {
  int idx = blockIdx.x * 256 + threadIdx.x;
  if (idx >= FRAG_TOT) return;
  int f, NR, Nreal; const float* Wg;
  if      (idx < 12288) { Wg = args.W[0]; f = idx;         NR = 6; Nreal = 81;  }
  else if (idx < 24576) { Wg = args.W[1]; f = idx - 12288; NR = 6; Nreal = 81;  }
  else if (idx < 43008) { Wg = args.W[2]; f = idx - 24576; NR = 9; Nreal = 135; }
  else if (idx < 55296) { Wg = args.W[3]; f = idx - 43008; NR = 6; Nreal = 81;  }
  else                  { Wg = args.W[4]; f = idx - 55296; NR = 6; Nreal = 81;  }
  int lane = f & 63;
  int rest = f >> 6;
  int nr   = rest % NR;
  int tmp  = rest / NR;
  int h    = tmp & 1;
  int kc   = tmp >> 1;
  int n = nr * 16 + (lane & 15);
  int k = kc * 32 + (lane >> 4) * 8;
  u32x4 a = {0, 0, 0, 0}, b = {0, 0, 0, 0};
  if (n < Nreal) {
    const float* Wp = Wg + (size_t)n * HID + k;
    a = *reinterpret_cast<const u32x4*>(Wp);
    b = *reinterpret_cast<const u32x4*>(Wp + 4);
  }
  short8 frag = h ? pack_lo(a, b) : pack_hi(a, b);
  *reinterpret_cast<short8*>(ws + (size_t)idx * 8) = frag;
}

// ---------- main GEMM body (per wave: 32 rows x full padded N) ----------
template <int GS, int NR>   // NR = padded N / 16 (6 or 9)
__device__ __forceinline__ void mfma_body(const float* __restrict__ tokens,
                                          const unsigned short* __restrict__ ws,
                                          const float* __restrict__ bias,
                                          float* __restrict__ out,
                                          int g, int gfrag, int jbase) {
  constexpr int N = 27 * GS;           // 81 or 135
  const int lane = threadIdx.x & 63;
  const int wave = threadIdx.x >> 6;
  const int m0   = blockIdx.x * 128 + wave * 32;  // wave owns rows m0..m0+31
  const int l15  = lane & 15;          // A row / B col / C col within tile
  const int koff = (lane >> 4) * 8;    // k sub-chunk

  // acc init = bias (broadcast along rows); padded cols get 0
  f32x4 acc[2][NR];
  #pragma unroll
  for (int nr = 0; nr < NR; ++nr) {
    int n = nr * 16 + l15;
    float bv = (n < N) ? bias[n] : 0.f;
    f32x4 b4 = {bv, bv, bv, bv};
    acc[0][nr] = b4;
    acc[1][nr] = b4;
  }

  const float* aptr0 = tokens + (size_t)(m0 + l15) * (5 * HID) + g * HID + koff;
  const float* aptr1 = aptr0 + (size_t)16 * (5 * HID);
  // fragment-major B: wave-load of fragment (kc,h,nr) is 1KB contiguous
  const unsigned short* bbase = ws + (size_t)gfrag + (size_t)lane * 8;

  // A double-buffer: cur holds kc's raw fp32, nxt receives kc+1's.
  u32x4 c0a = *reinterpret_cast<const u32x4*>(aptr0);
  u32x4 c0b = *reinterpret_cast<const u32x4*>(aptr0 + 4);
  u32x4 c1a = *reinterpret_cast<const u32x4*>(aptr1);
  u32x4 c1b = *reinterpret_cast<const u32x4*>(aptr1 + 4);

  #pragma unroll 2
  for (int kc = 0; kc < 16; ++kc) {
    // ---- issue ALL B loads for this kc (2*NR independent coalesced 16B) ----
    short8 bh[NR], bl[NR];
    #pragma unroll
    for (int nr = 0; nr < NR; ++nr) {
      const unsigned short* bp = bbase + (size_t)((kc * 2) * NR + nr) * 512;
      bh[nr] = *reinterpret_cast<const short8*>(bp);
      bl[nr] = *reinterpret_cast<const short8*>(bp + NR * 512);
    }
    // ---- issue next-kc A loads (HBM stream; kc=15 reloads kc=15, L1-hot) ----
    const int kn = (kc + 1 < 16) ? kc + 1 : 15;
    u32x4 n0a = *reinterpret_cast<const u32x4*>(aptr0 + kn * 32);
    u32x4 n0b = *reinterpret_cast<const u32x4*>(aptr0 + kn * 32 + 4);
    u32x4 n1a = *reinterpret_cast<const u32x4*>(aptr1 + kn * 32);
    u32x4 n1b = *reinterpret_cast<const u32x4*>(aptr1 + kn * 32 + 4);
    // ---- pack current A (VALU, overlaps in-flight loads) ----
    short8 ah0 = pack_hi(c0a, c0b), al0 = pack_lo(c0a, c0b);
    short8 ah1 = pack_hi(c1a, c1b), al1 = pack_lo(c1a, c1b);
    // ---- MFMA burst (consumes bh/bl in issue order -> rolling vmcnt) ----
    #pragma unroll
    for (int nr = 0; nr < NR; ++nr) {
      acc[0][nr] = __builtin_amdgcn_mfma_f32_16x16x32_bf16(ah0, bh[nr], acc[0][nr], 0, 0, 0);
      acc[1][nr] = __builtin_amdgcn_mfma_f32_16x16x32_bf16(ah1, bh[nr], acc[1][nr], 0, 0, 0);
      acc[0][nr] = __builtin_amdgcn_mfma_f32_16x16x32_bf16(al0, bh[nr], acc[0][nr], 0, 0, 0);
      acc[1][nr] = __builtin_amdgcn_mfma_f32_16x16x32_bf16(al1, bh[nr], acc[1][nr], 0, 0, 0);
      acc[0][nr] = __builtin_amdgcn_mfma_f32_16x16x32_bf16(ah0, bl[nr], acc[0][nr], 0, 0, 0);
      acc[1][nr] = __builtin_amdgcn_mfma_f32_16x16x32_bf16(ah1, bl[nr], acc[1][nr], 0, 0, 0);
    }
    c0a = n0a; c0b = n0b; c1a = n1a; c1b = n1b;
  }

  // epilogue: scatter store. C/D layout: col = lane&15, row = (lane>>4)*4 + reg
  #pragma unroll
  for (int mt = 0; mt < 2; ++mt) {
    int mrow = m0 + mt * 16 + (lane >> 4) * 4;
    #pragma unroll
    for (int nr = 0; nr < NR; ++nr) {
      int n = nr * 16 + l15;
      if (n < N) {
        int pt  = n / (3 * GS);
        int rem = n - pt * (3 * GS);
        int gl  = rem / 3;
        int c   = rem - gl * 3;
        int j   = (GS == 5) ? (gl == 0 ? 0 : gl + 6) : (jbase + gl);
        #pragma unroll
        for (int r = 0; r < 4; ++r) {
          int m  = mrow + r;
          int b  = m / TPCH;
          int tp = m - b * TPCH;
          out[((size_t)(b * 243 + tp * 9 + pt) * 17 + j) * 3 + c] = acc[mt][nr][r];
        }
      }
    }
  }
}

__global__ __launch_bounds__(256, 2)   // min 2 waves/EU -> 256-VGPR budget
void decoder_mfma(const float* __restrict__ tokens, Args args,
                  const unsigned short* __restrict__ ws, float* __restrict__ out) {
  const int g = blockIdx.y;   // uniform per block
  if (g == 2) {
    mfma_body<5, 9>(tokens, ws, args.bias[2], out, 2, 196608, 0);
  } else {
    int jbase = (g == 0) ? 1 : (g == 1) ? 4 : (g == 3) ? 11 : 14;
    int gfrag = (g == 0) ? 0 : (g == 1) ? 98304 : (g == 3) ? 344064 : 442368;
    mfma_body<3, 6>(tokens, ws, args.bias[g], out, g, gfrag, jbase);
  }
}

extern "C" void kernel_launch(void* const* d_in, const int* in_sizes, int n_in,
                              void* d_out, int out_size, void* d_ws, size_t ws_size,
                              hipStream_t stream) {
  const float* tokens = reinterpret_cast<const float*>(d_in[0]);
  Args args;
  for (int i = 0; i < 5; ++i) {
    args.W[i]    = reinterpret_cast<const float*>(d_in[1 + 2 * i]);
    args.bias[i] = reinterpret_cast<const float*>(d_in[2 + 2 * i]);
  }
  float* out = reinterpret_cast<float*>(d_out);
  unsigned short* ws = reinterpret_cast<unsigned short*>(d_ws);  // 1.03 MB

  convert_w<<<(FRAG_TOT + 255) / 256, 256, 0, stream>>>(args, ws);
  decoder_mfma<<<dim3(MROWS / 128, 5), 256, 0, stream>>>(tokens, args, ws, out);
}